// Round 14
// baseline (6637.647 us; speedup 1.0000x reference)
//
#include <hip/hip_runtime.h>

#define DEV static __device__ __forceinline__

typedef _Float16 h2 __attribute__((ext_vector_type(2)));

DEV float fdot2f(h2 a, h2 b, float c) {
#if __has_builtin(__builtin_amdgcn_fdot2)
  return __builtin_amdgcn_fdot2(a, b, c, false);
#else
  return c + (float)a.x * (float)b.x + (float)a.y * (float)b.y;
#endif
}

// LayerNorm over 3 elements: (x-m)/sqrt(v+eps)*g + b
DEV void ln3(float& a, float& b, float& c, const float* g, const float* bt) {
  float m = (a + b + c) * (1.0f / 3.0f);
  float d0 = a - m, d1 = b - m, d2 = c - m;
  float v = (d0 * d0 + d1 * d1 + d2 * d2) * (1.0f / 3.0f);
  float rs = rsqrtf(v + 1e-5f);
  a = fmaf(d0 * rs, g[0], bt[0]);
  b = fmaf(d1 * rs, g[1], bt[1]);
  c = fmaf(d2 * rs, g[2], bt[2]);
}

DEV unsigned pkh2(float a, float b) {
  h2 v = {(_Float16)a, (_Float16)b};
  return __builtin_bit_cast(unsigned, v);
}

// ---------------------------------------------------------------------------
// Prepack (round-6 layout, unchanged):
//  FAB[l] = 2048 x uint4 contiguous per layer:
//    [0..1023]    { pk(w1[2jp][d],w1[2jp+1][d]) d=0..2, pk(b1 pair) }
//    [1024..2047] { pk(w2[d][2jp],w2[d][2jp+1]) d=0..2, 0 }
//  SM[l][128] fp32 attn/LN scalars at float offset 196608 | GLOB[16] after
// ---------------------------------------------------------------------------
__global__ void __launch_bounds__(256) prepack_kernel(
    const float* ea_w, const float* ea_b, const float* ea_ow, const float* ea_ob,
    const float* el1g, const float* el1b, const float* el2g, const float* el2b,
    const float* ef1w, const float* ef1b, const float* ef2w, const float* ef2b,
    const float* eng, const float* enb,
    const float* dsw, const float* dsb, const float* dsow, const float* dsob,
    const float* dcw, const float* dcb, const float* dcow, const float* dcob,
    const float* dl1g, const float* dl1b, const float* dl2g, const float* dl2b,
    const float* dl3g, const float* dl3b,
    const float* df1w, const float* df1b, const float* df2w, const float* df2b,
    const float* dng, const float* dnb,
    float* ws) {
  const int l = blockIdx.x, tid = threadIdx.x;
  const bool enc = l < 12;
  const int li = enc ? l : l - 12;
  const float* f1w = (enc ? ef1w : df1w) + li * 2048 * 3;
  const float* f1b = (enc ? ef1b : df1b) + li * 2048;
  const float* f2w = (enc ? ef2w : df2w) + li * 3 * 2048;
  uint4* FA4 = (uint4*)ws + (size_t)l * 2048;
  uint4* FB4 = FA4 + 1024;
  for (int jp = tid; jp < 1024; jp += 256) {
    const int j0 = jp * 2, j1 = j0 + 1;
    uint4 A;
    A.x = pkh2(f1w[j0 * 3 + 0], f1w[j1 * 3 + 0]);
    A.y = pkh2(f1w[j0 * 3 + 1], f1w[j1 * 3 + 1]);
    A.z = pkh2(f1w[j0 * 3 + 2], f1w[j1 * 3 + 2]);
    A.w = pkh2(f1b[j0], f1b[j1]);
    FA4[jp] = A;
    uint4 Bv;
    Bv.x = pkh2(f2w[j0], f2w[j1]);
    Bv.y = pkh2(f2w[2048 + j0], f2w[2048 + j1]);
    Bv.z = pkh2(f2w[4096 + j0], f2w[4096 + j1]);
    Bv.w = 0u;
    FB4[jp] = Bv;
  }
  float* S = ws + 196608 + l * 128;
  if (tid == 0) {
    // 0-26 qkv W | 27-35 qkv b | 36-44 ow | 45-47 ob | 48-53 ln1 g,b
    // 54-59 ln2 g,b | 60-62 ffn b2
    const float* aw = (enc ? ea_w : dsw) + li * 27;
    const float* ab = (enc ? ea_b : dsb) + li * 9;
    const float* aow = (enc ? ea_ow : dsow) + li * 9;
    const float* aob = (enc ? ea_ob : dsob) + li * 3;
    for (int i = 0; i < 27; ++i) S[i] = aw[i];
    for (int i = 0; i < 9; ++i) S[27 + i] = ab[i];
    for (int i = 0; i < 9; ++i) S[36 + i] = aow[i];
    for (int i = 0; i < 3; ++i) S[45 + i] = aob[i];
    const float* p;
    p = (enc ? el1g : dl1g) + li * 3; for (int i = 0; i < 3; ++i) S[48 + i] = p[i];
    p = (enc ? el1b : dl1b) + li * 3; for (int i = 0; i < 3; ++i) S[51 + i] = p[i];
    p = (enc ? el2g : dl2g) + li * 3; for (int i = 0; i < 3; ++i) S[54 + i] = p[i];
    p = (enc ? el2b : dl2b) + li * 3; for (int i = 0; i < 3; ++i) S[57 + i] = p[i];
    p = (enc ? ef2b : df2b) + li * 3; for (int i = 0; i < 3; ++i) S[60 + i] = p[i];
    if (!enc) {
      // 64-72 cross qW | 73-75 qb | 76-84 cross ow | 85-87 ob | 88-93 ln3 g,b
      // 94-102 kW | 103-105 kb | 106-114 vW | 115-117 vb
      const float* cw = dcw + li * 27;
      for (int i = 0; i < 9; ++i) {
        S[64 + i] = cw[i];
        S[94 + i] = cw[9 + i];
        S[106 + i] = cw[18 + i];
      }
      const float* cb = dcb + li * 9;
      for (int i = 0; i < 3; ++i) {
        S[73 + i] = cb[i];
        S[103 + i] = cb[3 + i];
        S[115 + i] = cb[6 + i];
      }
      for (int i = 0; i < 9; ++i) S[76 + i] = dcow[li * 9 + i];
      for (int i = 0; i < 3; ++i) S[85 + i] = dcob[li * 3 + i];
      p = dl3g + li * 3; for (int i = 0; i < 3; ++i) S[88 + i] = p[i];
      p = dl3b + li * 3; for (int i = 0; i < 3; ++i) S[91 + i] = p[i];
    }
  }
  if (l == 0 && tid == 1) {
    float* G = ws + 196608 + 24 * 128;
    for (int i = 0; i < 3; ++i) {
      G[i] = eng[i]; G[3 + i] = enb[i];
      G[6 + i] = dng[i]; G[9 + i] = dnb[i];
    }
  }
}

// Packed-f16 FFN for NR rows; first two weight tiles arrive prefetched.
template <int NR>
DEV void ffn_core(const uint4* FA, uint4 pa0, uint4 pc0, uint4 pa1, uint4 pc1,
                  const float (&X0)[4], const float (&X1)[4], const float (&X2)[4],
                  float (&acc)[4][3], int lane) {
  h2 xd0[NR], xd1[NR], xd2[NR];
#pragma unroll
  for (int i = 0; i < NR; ++i) {
    xd0[i] = h2{(_Float16)X0[i], (_Float16)X0[i]};
    xd1[i] = h2{(_Float16)X1[i], (_Float16)X1[i]};
    xd2[i] = h2{(_Float16)X2[i], (_Float16)X2[i]};
  }
#pragma unroll
  for (int i = 0; i < NR; ++i) { acc[i][0] = 0.f; acc[i][1] = 0.f; acc[i][2] = 0.f; }
  const h2 z = {(_Float16)0, (_Float16)0};
  auto step = [&](uint4 a, uint4 c) {
    h2 wa0 = __builtin_bit_cast(h2, a.x), wa1 = __builtin_bit_cast(h2, a.y);
    h2 wa2 = __builtin_bit_cast(h2, a.z), bb = __builtin_bit_cast(h2, a.w);
    h2 wc0 = __builtin_bit_cast(h2, c.x), wc1 = __builtin_bit_cast(h2, c.y);
    h2 wc2 = __builtin_bit_cast(h2, c.z);
#pragma unroll
    for (int i = 0; i < NR; ++i) {
      h2 tt = wa0 * xd0[i] + wa1 * xd1[i] + wa2 * xd2[i] + bb;
      tt = __builtin_elementwise_max(tt, z);
      acc[i][0] = fdot2f(wc0, tt, acc[i][0]);
      acc[i][1] = fdot2f(wc1, tt, acc[i][1]);
      acc[i][2] = fdot2f(wc2, tt, acc[i][2]);
    }
  };
  step(pa0, pc0);
  step(pa1, pc1);
#pragma unroll 4
  for (int kk = 2; kk < 16; ++kk) {
    const int jp = lane + (kk << 6);
    step(FA[jp], FA[1024 + jp]);
  }
#pragma unroll
  for (int m = 1; m < 64; m <<= 1) {
#pragma unroll
    for (int i = 0; i < NR; ++i) {
      acc[i][0] += __shfl_xor(acc[i][0], m, 64);
      acc[i][1] += __shfl_xor(acc[i][1], m, 64);
      acc[i][2] += __shfl_xor(acc[i][2], m, 64);
    }
  }
}

// QKV projection phase (enc layer 0 / dec layer 0 each step) -> kvw.
// kvw row stride 13: q0..2 [3] k0..2(4-6) [7] v0..2(8-10).
DEV void qkv_phase(const float* sm, float* kvw, const float4* src4,
                   bool from_os, int R, int t, int tid) {
  const int r = tid >> 4, o = tid & 15;
  if (r < R && o < 9) {
    float4 xv = src4[r];
    float x0 = xv.x, x1 = xv.y, x2 = xv.z;
    if (from_os && r >= t) { x0 = 0.f; x1 = 0.f; x2 = 0.f; }  // zero rep
    kvw[r * 13 + o + o / 3] =
        fmaf(sm[o * 3], x0, fmaf(sm[o * 3 + 1], x1, fmaf(sm[o * 3 + 2], x2, sm[27 + o])));
  }
}

// ---------------------------------------------------------------------------
// Fully-fused layer: ONE phase, ONE barrier. Wave w owns rows {w,w+16,w+32,
// w+48}; lane (ig=l>>4, g=l&15): attention for row w+16*ig with (hd=g%3,
// chunk=g/3) for g<12. Chunk-reduce via shfl_down(6,3); head-combine via
// dynamic shfl (bpermute). Residual h lives in registers (hall, static idx).
// kvq double-buffered: read kvr, append next layer's QKV to kvw (race-free).
// Self-attn multiplicity arithmetic: p>t -> 0, p==t -> *(64-t). Pad rows
// compute finite garbage, discarded by nr.
// ---------------------------------------------------------------------------
template <bool DEC>
DEV void run_fused(const float* sm, const float* smn, const uint4* FA,
                   const float* ckv, const float* kvr, float* kvw,
                   float4* o_s4, float4* h4, const float* glob,
                   float (&hall)[4][3],
                   int R, int t, bool wpred, bool seed,
                   int wave, int lane) {
  // FFN weight prefetch (completes under the attention chain)
  uint4 pa0 = FA[lane], pc0 = FA[1024 + lane];
  uint4 pa1 = FA[64 + lane], pc1 = FA[1088 + lane];
  const int g = lane & 15, ig = lane >> 4;
  const int arow = wave + 16 * ig;
  // seed residual registers (dec l0: from o_s; enc l0: from h4)
  if (seed) {
    if (DEC) {
#pragma unroll
      for (int i = 0; i < 4; ++i) {
        const int r = wave + 16 * i;
        float4 xv = o_s4[r];
        const bool real = r < t;
        hall[i][0] = real ? xv.x : 0.f;
        hall[i][1] = real ? xv.y : 0.f;
        hall[i][2] = real ? xv.z : 0.f;
      }
    } else {
#pragma unroll
      for (int i = 0; i < 4; ++i) {
        float4 xv = h4[wave + 16 * i];
        hall[i][0] = xv.x; hall[i][1] = xv.y; hall[i][2] = xv.z;
      }
    }
  }
  // residual for this lane's attention row (static selects)
  float hr0 = hall[0][0], hr1 = hall[0][1], hr2 = hall[0][2];
  if (ig == 1) { hr0 = hall[1][0]; hr1 = hall[1][1]; hr2 = hall[1][2]; }
  else if (ig == 2) { hr0 = hall[2][0]; hr1 = hall[2][1]; hr2 = hall[2][2]; }
  else if (ig == 3) { hr0 = hall[3][0]; hr1 = hall[3][1]; hr2 = hall[3][2]; }
  const int hd = g % 3, ch = g / 3;
  // ---- self-attention partials (g<12), full 16-key unroll ----
  float den = 0.f, num = 0.f;
  if (g < 12) {
    const float q = kvr[arow * 13 + hd] * 1.44269504f;
#pragma unroll
    for (int pp = 0; pp < 16; ++pp) {
      const int p = ch * 16 + pp;
      float e = exp2f(q * kvr[p * 13 + 4 + hd]);
      if (DEC) {
        e = (p > t) ? 0.f : e;                     // pad keys dead
        e = (p == t) ? e * (float)(64 - t) : e;    // zero-rep multiplicity
      }
      den += e;
      num = fmaf(e, kvr[p * 13 + 8 + hd], num);
    }
  }
  // chunk-reduce (sum over g, g+3, g+6, g+9 -> valid at g<3)
  float dd = den + __shfl_down(den, 6, 64); dd += __shfl_down(dd, 3, 64);
  float nn = num + __shfl_down(num, 6, 64); nn += __shfl_down(nn, 3, 64);
  const float oh = __fdividef(nn, dd);
  const int base = lane & 48;
  const float oh0 = __shfl(oh, base, 64);
  const float oh1 = __shfl(oh, base + 1, 64);
  const float oh2 = __shfl(oh, base + 2, 64);
  // ---- C1: out-proj + residual + LN1 (all 16 lanes, redundant) ----
  float a0 = fmaf(sm[36], oh0, fmaf(sm[37], oh1, fmaf(sm[38], oh2, sm[45]))) + hr0;
  float a1 = fmaf(sm[39], oh0, fmaf(sm[40], oh1, fmaf(sm[41], oh2, sm[46]))) + hr1;
  float a2 = fmaf(sm[42], oh0, fmaf(sm[43], oh1, fmaf(sm[44], oh2, sm[47]))) + hr2;
  ln3(a0, a1, a2, sm + 48, sm + 51);
  float x0, x1, x2;
  if (DEC) {
    // ---- cross-attention in-wave ----
    float dc = 0.f, nc = 0.f;
    if (g < 12) {
      const float qc = fmaf(sm[64 + hd * 3], a0,
                       fmaf(sm[64 + hd * 3 + 1], a1,
                       fmaf(sm[64 + hd * 3 + 2], a2, sm[73 + hd]))) * 1.44269504f;
#pragma unroll
      for (int pp = 0; pp < 16; ++pp) {
        const int p = ch * 16 + pp;
        float e = exp2f(qc * ckv[p * 13 + 4 + hd]);
        dc += e;
        nc = fmaf(e, ckv[p * 13 + 8 + hd], nc);
      }
    }
    float dd2 = dc + __shfl_down(dc, 6, 64); dd2 += __shfl_down(dd2, 3, 64);
    float nn2 = nc + __shfl_down(nc, 6, 64); nn2 += __shfl_down(nn2, 3, 64);
    const float ohc = __fdividef(nn2, dd2);
    const float c0 = __shfl(ohc, base, 64);
    const float c1 = __shfl(ohc, base + 1, 64);
    const float c2 = __shfl(ohc, base + 2, 64);
    x0 = fmaf(sm[76], c0, fmaf(sm[77], c1, fmaf(sm[78], c2, sm[85]))) + a0;
    x1 = fmaf(sm[79], c0, fmaf(sm[80], c1, fmaf(sm[81], c2, sm[86]))) + a1;
    x2 = fmaf(sm[82], c0, fmaf(sm[83], c1, fmaf(sm[84], c2, sm[87]))) + a2;
    ln3(x0, x1, x2, sm + 54, sm + 57);
  } else {
    x0 = a0; x1 = a1; x2 = a2;
  }
  // ---- broadcast X of the wave's 4 rows to all lanes (uniform shfl) ----
  float X0[4], X1[4], X2[4];
#pragma unroll
  for (int i = 0; i < 4; ++i) {
    X0[i] = __shfl(x0, 16 * i, 64);
    X1[i] = __shfl(x1, 16 * i, 64);
    X2[i] = __shfl(x2, 16 * i, 64);
  }
  // ---- FFN + final LN + fused next-layer QKV append ----
  const int nr = (wave < R) ? (1 + (R - 1 - wave) / 16) : 0;
  if (nr > 0) {
    float acc[4][3];
    switch (nr) {
      case 1: ffn_core<1>(FA, pa0, pc0, pa1, pc1, X0, X1, X2, acc, lane); break;
      case 2: ffn_core<2>(FA, pa0, pc0, pa1, pc1, X0, X1, X2, acc, lane); break;
      case 3: ffn_core<3>(FA, pa0, pc0, pa1, pc1, X0, X1, X2, acc, lane); break;
      default: ffn_core<4>(FA, pa0, pc0, pa1, pc1, X0, X1, X2, acc, lane); break;
    }
    const float* fg = DEC ? sm + 88 : sm + 54;
    const float* fb = DEC ? sm + 91 : sm + 57;
#pragma unroll
    for (int i = 0; i < 4; ++i) {
      if (i < nr) {
        const int r = wave + 16 * i;
        float y0 = acc[i][0] + sm[60] + X0[i];
        float y1 = acc[i][1] + sm[61] + X1[i];
        float y2 = acc[i][2] + sm[62] + X2[i];
        ln3(y0, y1, y2, fg, fb);
        hall[i][0] = y0; hall[i][1] = y1; hall[i][2] = y2;
        if (lane == 0) {
          if (!DEC) h4[r] = float4{y0, y1, y2, 0.f};  // encoder-end needs h
          if (DEC && wpred && r == R - 1) {           // pred[t] = dec_norm
            float z0 = y0, z1 = y1, z2 = y2;
            ln3(z0, z1, z2, glob + 6, glob + 9);
            o_s4[t] = float4{z0, z1, z2, 0.f};
          }
        }
        if (smn && lane >= 9 * i && lane < 9 * i + 9) {
          const int o = lane - 9 * i;
          kvw[r * 13 + o + o / 3] =
              fmaf(smn[o * 3], y0,
              fmaf(smn[o * 3 + 1], y1, fmaf(smn[o * 3 + 2], y2, smn[27 + o])));
        }
      }
    }
  }
  __syncthreads();
}

// ---------------------------------------------------------------------------
// Main kernel: one block per batch element. Encoder -> cross K/V precompute
// -> 63 autoregressive decode steps with zero-row dedup -> output transpose.
// ---------------------------------------------------------------------------
__global__ void __launch_bounds__(1024) tf_kernel(const float* src, const float* angle,
                                                  const float* ws, float* out) {
  __shared__ float small_s[24][128];
  __shared__ float glob[16];
  __shared__ float kv[2][832];        // double-buffered QKV table, stride 13
  __shared__ __align__(16) float4 o_s4[64];
  __shared__ __align__(16) float4 h4[64];
  __shared__ float ckv13[12][832];    // cross K/V per decoder layer, stride 13
  const int b = blockIdx.x;
  const int tid = threadIdx.x, wave = tid >> 6, lane = tid & 63;
  const uint4* FABg = (const uint4*)ws;
  const float* SM = ws + 196608;
  const float* GB = SM + 24 * 128;
  for (int i = tid; i < 24 * 128; i += 1024) ((float*)small_s)[i] = SM[i];
  if (tid < 16) glob[tid] = GB[tid];
  if (tid < 64) {
    float x0 = src[b * 128 + tid];
    float x1 = src[b * 128 + 64 + tid];
    float x2 = angle[b];
    h4[tid] = float4{x0, x1, x2, 0.f};
    o_s4[tid] = (tid == 0) ? float4{x0, x1, x2, 0.f} : float4{0.f, 0.f, 0.f, 0.f};
  }
  __syncthreads();
  float hall[4][3];
  // ---- encoder: QKV for l0, then 12 fused layers ----
  qkv_phase(small_s[0], kv[0], h4, false, 64, 0, tid);
  __syncthreads();
  for (int l = 0; l < 12; ++l)
    run_fused<false>(small_s[l], (l < 11) ? small_s[l + 1] : nullptr,
                     FABg + (size_t)l * 2048, nullptr,
                     kv[l & 1], kv[(l + 1) & 1],
                     o_s4, h4, glob, hall, 64, 0, false, /*seed=*/l == 0,
                     wave, lane);
  // final encoder LN -> mem
  if (tid < 64) {
    float4 hx = h4[tid];
    float a = hx.x, bb = hx.y, c = hx.z;
    ln3(a, bb, c, glob + 0, glob + 3);
    h4[tid] = float4{a, bb, c, 0.f};
  }
  __syncthreads();
  // ---- precompute cross-attn K/V per decoder layer (stride-13 layout) ----
  if (wave < 12) {
    const float* sm = small_s[12 + wave];
    float4 hx = h4[lane];
#pragma unroll
    for (int hdd = 0; hdd < 3; ++hdd) {
      float k = fmaf(sm[94 + hdd * 3], hx.x,
                fmaf(sm[94 + hdd * 3 + 1], hx.y,
                fmaf(sm[94 + hdd * 3 + 2], hx.z, sm[103 + hdd])));
      float v = fmaf(sm[106 + hdd * 3], hx.x,
                fmaf(sm[106 + hdd * 3 + 1], hx.y,
                fmaf(sm[106 + hdd * 3 + 2], hx.z, sm[115 + hdd])));
      ckv13[wave][lane * 13 + 4 + hdd] = k;
      ckv13[wave][lane * 13 + 8 + hdd] = v;
    }
  }
  __syncthreads();
  // ---- autoregressive decode: step t fills o_s4[t] ----
  for (int t = 1; t < 64; ++t) {
    const int R = t + 1;
    qkv_phase(small_s[12], kv[0], o_s4, true, R, t, tid);
    __syncthreads();
    for (int li = 0; li < 12; ++li)
      run_fused<true>(small_s[12 + li], (li < 11) ? small_s[13 + li] : nullptr,
                      FABg + (size_t)(12 + li) * 2048, ckv13[li],
                      kv[li & 1], kv[(li + 1) & 1],
                      o_s4, nullptr, glob, hall, R, t,
                      /*wpred=*/li == 11, /*seed=*/li == 0, wave, lane);
  }
  // ---- output: [B,3,T] ----
  if (tid < 192) {
    int d = tid / 64, tt = tid % 64;
    out[b * 192 + tid] = ((const float*)o_s4)[tt * 4 + d];
  }
}

extern "C" void kernel_launch(void* const* d_in, const int* in_sizes, int n_in,
                              void* d_out, int out_size, void* d_ws, size_t ws_size,
                              hipStream_t stream) {
  (void)in_sizes; (void)n_in; (void)out_size; (void)ws_size;
  float* ws = (float*)d_ws;
  prepack_kernel<<<24, 256, 0, stream>>>(
      (const float*)d_in[2], (const float*)d_in[3], (const float*)d_in[4], (const float*)d_in[5],
      (const float*)d_in[6], (const float*)d_in[7], (const float*)d_in[8], (const float*)d_in[9],
      (const float*)d_in[10], (const float*)d_in[11], (const float*)d_in[12], (const float*)d_in[13],
      (const float*)d_in[14], (const float*)d_in[15],
      (const float*)d_in[16], (const float*)d_in[17], (const float*)d_in[18], (const float*)d_in[19],
      (const float*)d_in[20], (const float*)d_in[21], (const float*)d_in[22], (const float*)d_in[23],
      (const float*)d_in[24], (const float*)d_in[25], (const float*)d_in[26], (const float*)d_in[27],
      (const float*)d_in[28], (const float*)d_in[29],
      (const float*)d_in[30], (const float*)d_in[31], (const float*)d_in[32], (const float*)d_in[33],
      (const float*)d_in[34], (const float*)d_in[35],
      ws);
  tf_kernel<<<32, 1024, 0, stream>>>((const float*)d_in[0], (const float*)d_in[1], ws,
                                     (float*)d_out);
}